// Round 8
// baseline (188.252 us; speedup 1.0000x reference)
//
#include <hip/hip_runtime.h>
#include <hip/hip_bf16.h>
#include <math.h>

#define EPSC 1e-3f

typedef __attribute__((ext_vector_type(8)))  short  short8;
typedef __attribute__((ext_vector_type(4)))  float  float4v;
typedef __attribute__((ext_vector_type(16))) float  float16v;

static __device__ __forceinline__ unsigned short f2bf(float f) {
    union { float f; unsigned u; } x; x.f = f;
    unsigned r = x.u + 0x7FFFu + ((x.u >> 16) & 1u);
    return (unsigned short)(r >> 16);
}
static __device__ __forceinline__ unsigned pk_bf16(float lo, float hi) {
    union { __hip_bfloat162 h; unsigned u; } cv;
    cv.h = __float22bfloat162_rn(make_float2(lo, hi));
    return cv.u;
}
static __device__ __forceinline__ float4v mfma16(short8 a, short8 b, float4v c) {
    return __builtin_amdgcn_mfma_f32_16x16x32_bf16(a, b, c, 0, 0, 0);
}
static __device__ __forceinline__ float16v mfma32(short8 a, short8 b, float16v c) {
    return __builtin_amdgcn_mfma_f32_32x32x16_bf16(a, b, c, 0, 0, 0);
}

// ws layout (bytes)
#define OFF_NORM 0ull           // 256*256*4 = 262144
#define OFF_AT   262144ull      // 32 tiles * 32768 u16 * 2 = 2097152 (tile-swizzled)
#define OFF_BT   2359296ull     // 2097152
#define OFF_WOF  4456448ull     // 128*1024*2 = 262144 (K-split frag-linear)
#define OFF_WZF  4718592ull     // 128*128*2  = 32768  (16x16 frag-linear)

// ===================== merged pre-pass: LN/proj | cvt | norm =================
// blocks [0,512): LN+proj ; [512,1088): weight cvt ; [1088,1344): norm matrix
__global__ __launch_bounds__(256) void k_pre(
    const float* __restrict__ m, const float* __restrict__ mask,
    const float* __restrict__ ln_w, const float* __restrict__ ln_b,
    const float* __restrict__ w1, const float* __restrict__ b1,
    const float* __restrict__ w2, const float* __restrict__ b2,
    const float* __restrict__ w_out, const float* __restrict__ wz,
    unsigned short* __restrict__ aT, unsigned short* __restrict__ bT,
    unsigned short* __restrict__ wobF, unsigned short* __restrict__ wzF,
    float* __restrict__ normw)
{
    __shared__ unsigned short xs[64 * 266];   // 34048 B
    __shared__ unsigned short tr[64 * 76];    // 9728 B
    __shared__ float mkl[64];
    __shared__ float b12[64];
    int t = threadIdx.x;
    int b = blockIdx.x;

    if (b >= 1088) {           // ---------------- norm matrix ----------------
        int i = b - 1088, j = t;
        float acc = 0.f;
#pragma unroll 8
        for (int s = 0; s < 128; ++s)
            acc += mask[s * 256 + i] * mask[s * 256 + j];
        normw[i * 256 + j] = acc * (1.0f / 256.0f);
        return;
    }
    if (b >= 512) {            // ---------------- weight convert -------------
        int idx = (b - 512) * 256 + t;
        if (idx < 131072) {
            // wobF K-split frag-linear: slice = pw*2+kh (= k2 wave id)
            int j = idx & 7, lane = (idx >> 3) & 63, k16 = (idx >> 9) & 31;
            int kh = (idx >> 14) & 1, pw = (idx >> 15) & 3;
            int p = pw * 32 + (lane & 31);
            int k = kh * 512 + k16 * 16 + (lane >> 5) * 8 + j;
            wobF[idx] = f2bf(w_out[p * 1024 + k]);
        } else {
            int q = idx - 131072;   // 16384
            int j = q & 7, lane = (q >> 3) & 63, kk = (q >> 9) & 3, w = q >> 11;
            int p = w * 16 + (lane & 15);
            int k = kk * 32 + (lane >> 4) * 8 + j;
            wzF[q] = f2bf(wz[p * 128 + k]);
        }
        return;
    }

    // ---------------- LN + projections via MFMA (blocks 0..511) ----------------
    int w = t >> 6, lane = t & 63;
    int g = lane >> 4, l15 = lane & 15;
    int rr = lane >> 4, l16 = lane & 15;
    int n0 = (b & 31) * 8, s0 = (b >> 5) * 8;

    if (t < 64) {
        b12[t] = (t < 32) ? b1[t] : b2[t - 32];
        mkl[t] = mask[(s0 + (t >> 3)) * 256 + n0 + (t & 7)] * 0.0625f;   // 256^-0.5
    }

    float4 lw4[4], lb4[4];
#pragma unroll
    for (int q = 0; q < 4; ++q) {
        lw4[q] = *(const float4*)(ln_w + q * 64 + l16 * 4);
        lb4[q] = *(const float4*)(ln_b + q * 64 + l16 * 4);
    }

    // LN: 4 passes x 4 rows; 16 lanes per row
#pragma unroll
    for (int pass = 0; pass < 4; ++pass) {
        int r = w * 16 + pass * 4 + rr;
        const float* src = m + ((size_t)(s0 + (r >> 3)) * 256 + n0 + (r & 7)) * 256;
        float4 v[4];
#pragma unroll
        for (int q = 0; q < 4; ++q)
            v[q] = *(const float4*)(src + q * 64 + l16 * 4);
        float sum = 0.f, sq = 0.f;
#pragma unroll
        for (int q = 0; q < 4; ++q) {
            sum += v[q].x + v[q].y + v[q].z + v[q].w;
            sq  += v[q].x * v[q].x + v[q].y * v[q].y + v[q].z * v[q].z + v[q].w * v[q].w;
        }
#pragma unroll
        for (int mm = 1; mm <= 8; mm <<= 1) {
            sum += __shfl_xor(sum, mm);
            sq  += __shfl_xor(sq, mm);
        }
        float mu = sum * (1.f / 256.f);
        float rstd = rsqrtf(sq * (1.f / 256.f) - mu * mu + 1e-5f);
#pragma unroll
        for (int q = 0; q < 4; ++q) {
            uint2 u;
            u.x = pk_bf16((v[q].x - mu) * rstd * lw4[q].x + lb4[q].x,
                          (v[q].y - mu) * rstd * lw4[q].y + lb4[q].y);
            u.y = pk_bf16((v[q].z - mu) * rstd * lw4[q].z + lb4[q].z,
                          (v[q].w - mu) * rstd * lw4[q].w + lb4[q].w);
            *(uint2*)(xs + r * 266 + q * 64 + l16 * 4) = u;
        }
    }
    __syncthreads();   // covers b12/mkl too

    // MFMA: wave w -> rows [w*16,w*16+16) x 64 h; w1/w2 converted inline
    float4v zf4 = {0.f, 0.f, 0.f, 0.f};
    float4v acc[4]; acc[0] = zf4; acc[1] = zf4; acc[2] = zf4; acc[3] = zf4;
#pragma unroll
    for (int kk = 0; kk < 8; ++kk) {
        short8 af = *(const short8*)(xs + (w * 16 + l15) * 266 + kk * 32 + g * 8);
#pragma unroll
        for (int ht = 0; ht < 4; ++ht) {
            int h = ht * 16 + l15;
            const float* wr = (h < 32) ? (w1 + h * 256) : (w2 + (h - 32) * 256);
            float4 wa = *(const float4*)(wr + kk * 32 + g * 8);
            float4 wb = *(const float4*)(wr + kk * 32 + g * 8 + 4);
            union { short8 s; unsigned u[4]; } bfr;
            bfr.u[0] = pk_bf16(wa.x, wa.y);
            bfr.u[1] = pk_bf16(wa.z, wa.w);
            bfr.u[2] = pk_bf16(wb.x, wb.y);
            bfr.u[3] = pk_bf16(wb.z, wb.w);
            acc[ht] = mfma16(af, bfr.s, acc[ht]);
        }
    }
#pragma unroll
    for (int ht = 0; ht < 4; ++ht) {
        int h = ht * 16 + l15;
        float bias = b12[h];
        int rbase = w * 16 + g * 4;
        uint2 u;
        u.x = pk_bf16((acc[ht][0] + bias) * mkl[rbase + 0], (acc[ht][1] + bias) * mkl[rbase + 1]);
        u.y = pk_bf16((acc[ht][2] + bias) * mkl[rbase + 2], (acc[ht][3] + bias) * mkl[rbase + 3]);
        *(uint2*)(tr + h * 76 + rbase) = u;
    }
    __syncthreads();

    // gather 8-s runs; store into TILE-SWIZZLED global layout (16B units)
#pragma unroll
    for (int it = 0; it < 2; ++it) {
        int q = t + it * 256;
        int h = q >> 3, n_l = q & 7;
        unsigned short vv[8];
#pragma unroll
        for (int s_l = 0; s_l < 8; ++s_l)
            vv[s_l] = tr[h * 76 + s_l * 8 + n_l];
        uint4 u;
        u.x = (unsigned)vv[0] | ((unsigned)vv[1] << 16);
        u.y = (unsigned)vv[2] | ((unsigned)vv[3] << 16);
        u.z = (unsigned)vv[4] | ((unsigned)vv[5] << 16);
        u.w = (unsigned)vv[6] | ((unsigned)vv[7] << 16);
        int row = n_l * 32 + (h & 31);                         // tile-local row
        int dwcol = (s0 >> 1) ^ ((row & 7) << 2);              // baked swizzle
        unsigned short* dst = ((h < 32) ? aT : bT)
            + (size_t)(n0 >> 3) * 32768 + row * 128 + dwcol * 2;
        *(uint4*)dst = u;
    }
}

// ====== fused: GEMM1 + GEMM2 (pair-half passes) + epilogue + wz; 64 KiB LDS ==
__global__ __launch_bounds__(512, 2) void k2_fused(
    const unsigned short* __restrict__ aT, const unsigned short* __restrict__ bT,
    const unsigned short* __restrict__ wobF, const unsigned short* __restrict__ wzF,
    const float* __restrict__ b_out, const float* __restrict__ normw,
    const float* __restrict__ ln_ow, const float* __restrict__ ln_ob,
    const float* __restrict__ bz, float* __restrict__ out)
{
    __shared__ char smem[65536];
    unsigned* s32 = (unsigned*)smem;                        // As dw[0,8192) Bs dw[8192,16384)
    unsigned* oL = (unsigned*)smem;                         // 32 pairs x 512 dw (swizzled)
    float* zA = (float*)smem;                               // [32][132] f32 (kh=0)
    float* zB = (float*)(smem + 16896);                     // [32][132] f32 (kh=1)
    unsigned short* lnL = (unsigned short*)(smem + 33792);  // [32][136] bf16

    int t = threadIdx.x;
    int w = t >> 6, lane = t & 63;
    int g = lane >> 4, l15 = lane & 15;
    int bj = blockIdx.x, bi = blockIdx.y;
    int wn = w & 1, wm = w >> 1;

    const unsigned* Ag = (const unsigned*)(aT + (size_t)bi * 32768);
    const unsigned* Bg = (const unsigned*)(bT + (size_t)bj * 32768);

    float4v zf4 = {0.f, 0.f, 0.f, 0.f};
    float4v acc[4][8];
#pragma unroll
    for (int fm = 0; fm < 4; ++fm)
#pragma unroll
        for (int fn = 0; fn < 8; ++fn) acc[fm][fn] = zf4;

    // ---------------- GEMM1: K staged in two 32-dw halves ---------------------
    for (int kh = 0; kh < 2; ++kh) {
        if (kh) __syncthreads();
#pragma unroll
        for (int it = 0; it < 4; ++it) {
            int idx = t + it * 512;               // [0,2048)
            int row = idx >> 3, c4 = idx & 7;
            int off = (c4 * 4) ^ ((row & 7) << 2);   // pre-swizzled positions
            *(uint4*)(s32 + row * 32 + off) = *(const uint4*)(Ag + row * 64 + kh * 32 + off);
            *(uint4*)(s32 + 8192 + row * 32 + off) = *(const uint4*)(Bg + row * 64 + kh * 32 + off);
        }
        __syncthreads();
        int sw = (l15 & 7) << 2;
#pragma unroll
        for (int kk2 = 0; kk2 < 2; ++kk2) {
            int col = (kk2 * 16 + g * 4) ^ sw;
            short8 af[4], bf[8];
#pragma unroll
            for (int fm = 0; fm < 4; ++fm)
                af[fm] = *(const short8*)((const char*)(s32 + (wm * 64 + fm * 16 + l15) * 32 + col));
#pragma unroll
            for (int fn = 0; fn < 8; ++fn)
                bf[fn] = *(const short8*)((const char*)(s32 + 8192 + (wn * 128 + fn * 16 + l15) * 32 + col));
#pragma unroll
            for (int fm = 0; fm < 4; ++fm)
#pragma unroll
                for (int fn = 0; fn < 8; ++fn)   // swapped: D reg-dim = je, l15-dim = ic
                    acc[fm][fn] = mfma16(bf[fn], af[fm], acc[fm][fn]);
        }
    }

    // hoisted epilogue params
    const float4 loA = *(const float4*)(ln_ow + l15 * 8);
    const float4 loB = *(const float4*)(ln_ow + l15 * 8 + 4);
    const float4 lbA = *(const float4*)(ln_ob + l15 * 8);
    const float4 lbB = *(const float4*)(ln_ob + l15 * 8 + 4);
    const float4 boA = *(const float4*)(b_out + l15 * 8);
    const float4 boB = *(const float4*)(b_out + l15 * 8 + 4);
    float lw8[8] = {loA.x, loA.y, loA.z, loA.w, loB.x, loB.y, loB.z, loB.w};
    float lb8[8] = {lbA.x, lbA.y, lbA.z, lbA.w, lbB.x, lbB.y, lbB.z, lbB.w};
    float bo8[8] = {boA.x, boA.y, boA.z, boA.w, boB.x, boB.y, boB.z, boB.w};
    float bzq = bz[w * 16 + l15];

    // ---------------- two pair-half passes ------------------------------------
    for (int p = 0; p < 2; ++p) {
        __syncthreads();   // oL region free (staging/lnL reads of prev phase done)
        if ((wm >> 1) == p) {
#pragma unroll
            for (int fm = 0; fm < 4; ++fm) {
#pragma unroll
                for (int fn = 0; fn < 8; ++fn) {
                    int pl = ((wm & 1) * 2 + (fm >> 1)) * 8 + wn * 4 + (fn >> 1); // [0,32)
                    int c = (fm & 1) * 16 + l15;
                    int o = (fn & 1) * 8 + 2 * g;
                    int off = c * 16 + o;
                    int dw = pl * 512 + (off ^ ((((pl & 7) ^ (off >> 6)) & 7) << 2));
                    float4v a4 = acc[fm][fn];
                    uint2 u;
                    u.x = pk_bf16(a4[0], a4[1]);
                    u.y = pk_bf16(a4[2], a4[3]);
                    *(uint2*)(oL + dw) = u;
                }
            }
        }
        __syncthreads();

        // GEMM2 (32x32x16, K-split): 32 pairs x 128 p
        {
            int kh = w & 1, pw = w >> 1;
            int l31 = lane & 31, h2 = lane >> 5;
            float16v a32 = {0.f};
            const unsigned short* wbase = wobF + (size_t)w * 16384;
#pragma unroll 8
            for (int k16 = 0; k16 < 32; ++k16) {
                int kg = kh * 32 + k16;
                int off = kg * 8 + h2 * 4;
                int dws = off ^ ((((l31 & 7) ^ (off >> 6)) & 7) << 2);
                short8 b2 = *(const short8*)(wbase + (size_t)(k16 * 64 + lane) * 8);
                short8 aA = *(const short8*)(oL + l31 * 512 + dws);
                a32 = mfma32(aA, b2, a32);
            }
            __syncthreads();   // all oL reads done; region becomes zA/zB
            float* zdst = kh ? zB : zA;
#pragma unroll
            for (int reg = 0; reg < 16; ++reg) {
                int pr = (reg & 3) + 8 * (reg >> 2) + 4 * h2;
                zdst[pr * 132 + pw * 32 + l31] = a32[reg];
            }
        }
        __syncthreads();

        // epilogue: +b_out, /(eps+norm), gelu, LN(128); 32 pairs (wave: pl=w*4+g)
        {
            int pl = w * 4 + g;
            int iG = bi * 8 + p * 4 + (pl >> 3), jG = bj * 8 + (pl & 7);
            float inv = 1.0f / (EPSC + normw[iG * 256 + jG]);
            float4v zA0 = *(const float4v*)(zA + pl * 132 + l15 * 8);
            float4v zA1 = *(const float4v*)(zA + pl * 132 + l15 * 8 + 4);
            float4v zB0 = *(const float4v*)(zB + pl * 132 + l15 * 8);
            float4v zB1 = *(const float4v*)(zB + pl * 132 + l15 * 8 + 4);
            float vals[8];
            float sum = 0.f, sq = 0.f;
#pragma unroll
            for (int e2 = 0; e2 < 8; ++e2) {
                float v = ((e2 < 4) ? (zA0[e2] + zB0[e2]) : (zA1[e2 - 4] + zB1[e2 - 4])) + bo8[e2];
                v *= inv;
                v = 0.5f * v * (1.0f + erff(v * 0.70710678118654752f));
                vals[e2] = v; sum += v; sq += v * v;
            }
#pragma unroll
            for (int mm = 1; mm <= 8; mm <<= 1) {
                sum += __shfl_xor(sum, mm);
                sq  += __shfl_xor(sq, mm);
            }
            float mu = sum * (1.0f / 128.0f);
            float rstd = rsqrtf(sq * (1.0f / 128.0f) - mu * mu + 1e-5f);
            uint4 upk;
            upk.x = pk_bf16((vals[0] - mu) * rstd * lw8[0] + lb8[0],
                            (vals[1] - mu) * rstd * lw8[1] + lb8[1]);
            upk.y = pk_bf16((vals[2] - mu) * rstd * lw8[2] + lb8[2],
                            (vals[3] - mu) * rstd * lw8[3] + lb8[3]);
            upk.z = pk_bf16((vals[4] - mu) * rstd * lw8[4] + lb8[4],
                            (vals[5] - mu) * rstd * lw8[5] + lb8[5]);
            upk.w = pk_bf16((vals[6] - mu) * rstd * lw8[6] + lb8[6],
                            (vals[7] - mu) * rstd * lw8[7] + lb8[7]);
            *(uint4*)(lnL + pl * 136 + l15 * 8) = upk;
        }
        __syncthreads();

        // wz matmul + bz, store; q-slice 16 per wave; 32 pairs (fr=0,1)
        {
            float4v acc3[2]; acc3[0] = zf4; acc3[1] = zf4;
#pragma unroll
            for (int kk = 0; kk < 4; ++kk) {
                short8 bfw = *(const short8*)(wzF + ((size_t)(w * 4 + kk) * 64 + lane) * 8);
#pragma unroll
                for (int fr = 0; fr < 2; ++fr) {
                    short8 af3 = *(const short8*)(lnL + (fr * 16 + l15) * 136 + kk * 32 + g * 8);
                    acc3[fr] = mfma16(af3, bfw, acc3[fr]);
                }
            }
#pragma unroll
            for (int fr = 0; fr < 2; ++fr) {
#pragma unroll
                for (int r = 0; r < 4; ++r) {
                    int pl = fr * 16 + g * 4 + r;
                    int row = (bi * 8 + p * 4 + (pl >> 3)) * 256 + bj * 8 + (pl & 7);
                    out[(size_t)row * 128 + w * 16 + l15] = acc3[fr][r] + bzq;
                }
            }
        }
    }
}

extern "C" void kernel_launch(void* const* d_in, const int* in_sizes, int n_in,
                              void* d_out, int out_size, void* d_ws, size_t ws_size,
                              hipStream_t stream) {
    const float* m      = (const float*)d_in[0];
    const float* mask   = (const float*)d_in[1];
    const float* ln_w   = (const float*)d_in[2];
    const float* ln_b   = (const float*)d_in[3];
    const float* w1     = (const float*)d_in[4];
    const float* b1     = (const float*)d_in[5];
    const float* w2     = (const float*)d_in[6];
    const float* b2     = (const float*)d_in[7];
    const float* w_out  = (const float*)d_in[8];
    const float* b_out  = (const float*)d_in[9];
    const float* ln_ow  = (const float*)d_in[10];
    const float* ln_ob  = (const float*)d_in[11];
    const float* wz     = (const float*)d_in[12];
    const float* bz     = (const float*)d_in[13];
    float* out = (float*)d_out;
    char*  ws  = (char*)d_ws;

    float* normw          = (float*)(ws + OFF_NORM);
    unsigned short* aTb   = (unsigned short*)(ws + OFF_AT);
    unsigned short* bTb   = (unsigned short*)(ws + OFF_BT);
    unsigned short* wobF  = (unsigned short*)(ws + OFF_WOF);
    unsigned short* wzF   = (unsigned short*)(ws + OFF_WZF);

    k_pre<<<dim3(1344), dim3(256), 0, stream>>>(m, mask, ln_w, ln_b, w1, b1, w2, b2,
                                                w_out, wz, aTb, bTb, wobF, wzF, normw);
    k2_fused<<<dim3(32, 32), dim3(512), 0, stream>>>(aTb, bTb, wobF, wzF, b_out, normw,
                                                     ln_ow, ln_ob, bz, out);
}

// Round 9
// 176.226 us; speedup vs baseline: 1.0682x; 1.0682x over previous
//
#include <hip/hip_runtime.h>
#include <hip/hip_bf16.h>
#include <math.h>

#define EPSC 1e-3f

typedef __attribute__((ext_vector_type(8)))  short  short8;
typedef __attribute__((ext_vector_type(4)))  float  float4v;
typedef __attribute__((ext_vector_type(16))) float  float16v;

static __device__ __forceinline__ unsigned short f2bf(float f) {
    union { float f; unsigned u; } x; x.f = f;
    unsigned r = x.u + 0x7FFFu + ((x.u >> 16) & 1u);
    return (unsigned short)(r >> 16);
}
static __device__ __forceinline__ unsigned pk_bf16(float lo, float hi) {
    union { __hip_bfloat162 h; unsigned u; } cv;
    cv.h = __float22bfloat162_rn(make_float2(lo, hi));
    return cv.u;
}
static __device__ __forceinline__ float4v mfma16(short8 a, short8 b, float4v c) {
    return __builtin_amdgcn_mfma_f32_16x16x32_bf16(a, b, c, 0, 0, 0);
}
static __device__ __forceinline__ float16v mfma32(short8 a, short8 b, float16v c) {
    return __builtin_amdgcn_mfma_f32_32x32x16_bf16(a, b, c, 0, 0, 0);
}

// ws layout (bytes)
#define OFF_NORM 0ull           // 256*256*4 = 262144
#define OFF_AT   262144ull      // 32 tiles * 32768 u16 * 2 = 2097152 (tile-swizzled)
#define OFF_BT   2359296ull     // 2097152
#define OFF_WOF  4456448ull     // 128*1024*2 = 262144 (K-split frag-linear)
#define OFF_WZF  4718592ull     // 128*128*2  = 32768  (16x16 frag-linear)

// ===================== merged pre-pass: LN/proj | cvt | norm =================
// blocks [0,512): LN+proj ; [512,1088): weight cvt ; [1088,1344): norm matrix
__global__ __launch_bounds__(256) void k_pre(
    const float* __restrict__ m, const float* __restrict__ mask,
    const float* __restrict__ ln_w, const float* __restrict__ ln_b,
    const float* __restrict__ w1, const float* __restrict__ b1,
    const float* __restrict__ w2, const float* __restrict__ b2,
    const float* __restrict__ w_out, const float* __restrict__ wz,
    unsigned short* __restrict__ aT, unsigned short* __restrict__ bT,
    unsigned short* __restrict__ wobF, unsigned short* __restrict__ wzF,
    float* __restrict__ normw)
{
    __shared__ unsigned short xs[64 * 266];   // 34048 B
    __shared__ unsigned short tr[64 * 76];    // 9728 B
    __shared__ float mkl[64];
    __shared__ float b12[64];
    int t = threadIdx.x;
    int b = blockIdx.x;

    if (b >= 1088) {           // ---------------- norm matrix ----------------
        int i = b - 1088, j = t;
        float acc = 0.f;
#pragma unroll 8
        for (int s = 0; s < 128; ++s)
            acc += mask[s * 256 + i] * mask[s * 256 + j];
        normw[i * 256 + j] = acc * (1.0f / 256.0f);
        return;
    }
    if (b >= 512) {            // ---------------- weight convert -------------
        int idx = (b - 512) * 256 + t;
        if (idx < 131072) {
            // wobF K-split frag-linear: slice = pw*2+kh
            int j = idx & 7, lane = (idx >> 3) & 63, k16 = (idx >> 9) & 31;
            int kh = (idx >> 14) & 1, pw = (idx >> 15) & 3;
            int p = pw * 32 + (lane & 31);
            int k = kh * 512 + k16 * 16 + (lane >> 5) * 8 + j;
            wobF[idx] = f2bf(w_out[p * 1024 + k]);
        } else {
            int q = idx - 131072;   // 16384
            int j = q & 7, lane = (q >> 3) & 63, kk = (q >> 9) & 3, w = q >> 11;
            int p = w * 16 + (lane & 15);
            int k = kk * 32 + (lane >> 4) * 8 + j;
            wzF[q] = f2bf(wz[p * 128 + k]);
        }
        return;
    }

    // ---------------- LN + projections via MFMA (blocks 0..511) ----------------
    int w = t >> 6, lane = t & 63;
    int g = lane >> 4, l15 = lane & 15;
    int rr = lane >> 4, l16 = lane & 15;
    int n0 = (b & 31) * 8, s0 = (b >> 5) * 8;

    if (t < 64) {
        b12[t] = (t < 32) ? b1[t] : b2[t - 32];
        mkl[t] = mask[(s0 + (t >> 3)) * 256 + n0 + (t & 7)] * 0.0625f;   // 256^-0.5
    }

    float4 lw4[4], lb4[4];
#pragma unroll
    for (int q = 0; q < 4; ++q) {
        lw4[q] = *(const float4*)(ln_w + q * 64 + l16 * 4);
        lb4[q] = *(const float4*)(ln_b + q * 64 + l16 * 4);
    }

    // LN: 4 passes x 4 rows; 16 lanes per row
#pragma unroll
    for (int pass = 0; pass < 4; ++pass) {
        int r = w * 16 + pass * 4 + rr;
        const float* src = m + ((size_t)(s0 + (r >> 3)) * 256 + n0 + (r & 7)) * 256;
        float4 v[4];
#pragma unroll
        for (int q = 0; q < 4; ++q)
            v[q] = *(const float4*)(src + q * 64 + l16 * 4);
        float sum = 0.f, sq = 0.f;
#pragma unroll
        for (int q = 0; q < 4; ++q) {
            sum += v[q].x + v[q].y + v[q].z + v[q].w;
            sq  += v[q].x * v[q].x + v[q].y * v[q].y + v[q].z * v[q].z + v[q].w * v[q].w;
        }
#pragma unroll
        for (int mm = 1; mm <= 8; mm <<= 1) {
            sum += __shfl_xor(sum, mm);
            sq  += __shfl_xor(sq, mm);
        }
        float mu = sum * (1.f / 256.f);
        float rstd = rsqrtf(sq * (1.f / 256.f) - mu * mu + 1e-5f);
#pragma unroll
        for (int q = 0; q < 4; ++q) {
            uint2 u;
            u.x = pk_bf16((v[q].x - mu) * rstd * lw4[q].x + lb4[q].x,
                          (v[q].y - mu) * rstd * lw4[q].y + lb4[q].y);
            u.y = pk_bf16((v[q].z - mu) * rstd * lw4[q].z + lb4[q].z,
                          (v[q].w - mu) * rstd * lw4[q].w + lb4[q].w);
            *(uint2*)(xs + r * 266 + q * 64 + l16 * 4) = u;
        }
    }
    __syncthreads();   // covers b12/mkl too

    // MFMA: wave w -> rows [w*16,w*16+16) x 64 h; w1/w2 converted inline
    float4v zf4 = {0.f, 0.f, 0.f, 0.f};
    float4v acc[4]; acc[0] = zf4; acc[1] = zf4; acc[2] = zf4; acc[3] = zf4;
#pragma unroll
    for (int kk = 0; kk < 8; ++kk) {
        short8 af = *(const short8*)(xs + (w * 16 + l15) * 266 + kk * 32 + g * 8);
#pragma unroll
        for (int ht = 0; ht < 4; ++ht) {
            int h = ht * 16 + l15;
            const float* wr = (h < 32) ? (w1 + h * 256) : (w2 + (h - 32) * 256);
            float4 wa = *(const float4*)(wr + kk * 32 + g * 8);
            float4 wb = *(const float4*)(wr + kk * 32 + g * 8 + 4);
            union { short8 s; unsigned u[4]; } bfr;
            bfr.u[0] = pk_bf16(wa.x, wa.y);
            bfr.u[1] = pk_bf16(wa.z, wa.w);
            bfr.u[2] = pk_bf16(wb.x, wb.y);
            bfr.u[3] = pk_bf16(wb.z, wb.w);
            acc[ht] = mfma16(af, bfr.s, acc[ht]);
        }
    }
#pragma unroll
    for (int ht = 0; ht < 4; ++ht) {
        int h = ht * 16 + l15;
        float bias = b12[h];
        int rbase = w * 16 + g * 4;
        uint2 u;
        u.x = pk_bf16((acc[ht][0] + bias) * mkl[rbase + 0], (acc[ht][1] + bias) * mkl[rbase + 1]);
        u.y = pk_bf16((acc[ht][2] + bias) * mkl[rbase + 2], (acc[ht][3] + bias) * mkl[rbase + 3]);
        *(uint2*)(tr + h * 76 + rbase) = u;
    }
    __syncthreads();

    // gather 8-s runs; store into TILE-SWIZZLED global layout (16B units)
#pragma unroll
    for (int it = 0; it < 2; ++it) {
        int q = t + it * 256;
        int h = q >> 3, n_l = q & 7;
        unsigned short vv[8];
#pragma unroll
        for (int s_l = 0; s_l < 8; ++s_l)
            vv[s_l] = tr[h * 76 + s_l * 8 + n_l];
        uint4 u;
        u.x = (unsigned)vv[0] | ((unsigned)vv[1] << 16);
        u.y = (unsigned)vv[2] | ((unsigned)vv[3] << 16);
        u.z = (unsigned)vv[4] | ((unsigned)vv[5] << 16);
        u.w = (unsigned)vv[6] | ((unsigned)vv[7] << 16);
        int row = n_l * 32 + (h & 31);                         // tile-local row
        int dwcol = (s0 >> 1) ^ ((row & 7) << 2);              // baked swizzle
        unsigned short* dst = ((h < 32) ? aT : bT)
            + (size_t)(n0 >> 3) * 32768 + row * 128 + dwcol * 2;
        *(uint4*)dst = u;
    }
}

// ====== fused: GEMM1 + GEMM2 + epilogue + wz; 1024 thr, 128 KiB, 4 waves/SIMD
__global__ __launch_bounds__(1024, 4) void k2_fused(
    const unsigned short* __restrict__ aT, const unsigned short* __restrict__ bT,
    const unsigned short* __restrict__ wobF, const unsigned short* __restrict__ wzF,
    const float* __restrict__ b_out, const float* __restrict__ normw,
    const float* __restrict__ ln_ow, const float* __restrict__ ln_ob,
    const float* __restrict__ bz, float* __restrict__ out)
{
    __shared__ char smem[131072];
    unsigned* s32 = (unsigned*)smem;                        // A dw[0,16384) B dw[16384,32768)
    unsigned* oL = (unsigned*)smem;                         // 64 pairs x 512 dw (swizzled)
    float* zA = (float*)smem;                               // [64][132] f32 (kh=0)
    float* zB = (float*)(smem + 33792);                     // [64][132] f32 (kh=1)
    unsigned short* lnL = (unsigned short*)(smem + 67584);  // [64][136] bf16

    int t = threadIdx.x;
    int w = t >> 6, lane = t & 63;
    int g = lane >> 4, l15 = lane & 15;
    int bj = blockIdx.x, bi = blockIdx.y;
    int wm = w >> 2, wn = w & 3;   // wm: ic-quarter (64 rows), wn: je-quarter (64 rows)

    // ---------------- stage A,B: pure linear copy (global pre-swizzled) -------
    {
        const uint4* Agv = (const uint4*)(aT + (size_t)bi * 32768);
        const uint4* Bgv = (const uint4*)(bT + (size_t)bj * 32768);
#pragma unroll
        for (int it = 0; it < 4; ++it) {
            int q = t + it * 1024;
            *(uint4*)(s32 + q * 4) = Agv[q];
            *(uint4*)(s32 + 16384 + q * 4) = Bgv[q];
        }
    }
    __syncthreads();

    // ---------------- GEMM1: 64(ic) x 64(je) per wave -------------------------
    float4v zf4 = {0.f, 0.f, 0.f, 0.f};
    float4v acc[4][4];
#pragma unroll
    for (int fm = 0; fm < 4; ++fm)
#pragma unroll
        for (int fn = 0; fn < 4; ++fn) acc[fm][fn] = zf4;

    {
        int sw = (l15 & 7) << 2;
#pragma unroll
        for (int kk = 0; kk < 4; ++kk) {
            int col = (kk * 16 + g * 4) ^ sw;
            short8 af[4], bf[4];
#pragma unroll
            for (int fm = 0; fm < 4; ++fm)
                af[fm] = *(const short8*)((const char*)(s32 + (wm * 64 + fm * 16 + l15) * 64 + col));
#pragma unroll
            for (int fn = 0; fn < 4; ++fn)
                bf[fn] = *(const short8*)((const char*)(s32 + 16384 + (wn * 64 + fn * 16 + l15) * 64 + col));
#pragma unroll
            for (int fm = 0; fm < 4; ++fm)
#pragma unroll
                for (int fn = 0; fn < 4; ++fn)   // swapped: D reg-dim = je, l15-dim = ic
                    acc[fm][fn] = mfma16(bf[fn], af[fm], acc[fm][fn]);
        }
    }
    __syncthreads();   // staging dead; region becomes oL

    // ---- pack outer -> LDS bf16; sigma(pl,off) = off ^ (((pl&7)^(off>>6))<<2)
#pragma unroll
    for (int fm = 0; fm < 4; ++fm) {
#pragma unroll
        for (int fn = 0; fn < 4; ++fn) {
            int pl = (wm * 2 + (fm >> 1)) * 8 + wn * 2 + (fn >> 1);
            int c = (fm & 1) * 16 + l15;
            int o = (fn & 1) * 8 + 2 * g;
            int off = c * 16 + o;
            int dw = pl * 512 + (off ^ ((((pl & 7) ^ (off >> 6)) & 7) << 2));
            float4v a4 = acc[fm][fn];
            uint2 u;
            u.x = pk_bf16(a4[0], a4[1]);
            u.y = pk_bf16(a4[2], a4[3]);
            *(uint2*)(oL + dw) = u;
        }
    }
    __syncthreads();

    // ------- GEMM2 (32x32x16): wave = (pw 4) x (kh 2) x (ph 2) ---------------
    {
        int pw = w & 3, kh = (w >> 2) & 1, ph = w >> 3;
        int l31 = lane & 31, h2 = lane >> 5;
        int pairR = ph * 32 + l31;
        float16v a32 = {0.f};
        const unsigned short* wbase = wobF + (size_t)(pw * 2 + kh) * 16384;
#pragma unroll 8
        for (int k16 = 0; k16 < 32; ++k16) {
            int kg = kh * 32 + k16;
            int off = kg * 8 + h2 * 4;
            int dws = off ^ ((((pairR & 7) ^ (off >> 6)) & 7) << 2);
            short8 b2 = *(const short8*)(wbase + (size_t)(k16 * 64 + lane) * 8);
            short8 aA = *(const short8*)(oL + pairR * 512 + dws);
            a32 = mfma32(aA, b2, a32);
        }
        __syncthreads();   // all oL reads done; region becomes zA/zB
        float* zdst = kh ? zB : zA;
#pragma unroll
        for (int reg = 0; reg < 16; ++reg) {
            int pr = (reg & 3) + 8 * (reg >> 2) + 4 * h2;
            zdst[(ph * 32 + pr) * 132 + pw * 32 + l31] = a32[reg];
        }
    }
    __syncthreads();

    // ---------------- epilogue: +b_out, /(eps+norm), gelu, LN(128) ------------
    {
        const float4 loA = *(const float4*)(ln_ow + l15 * 8);
        const float4 loB = *(const float4*)(ln_ow + l15 * 8 + 4);
        const float4 lbA = *(const float4*)(ln_ob + l15 * 8);
        const float4 lbB = *(const float4*)(ln_ob + l15 * 8 + 4);
        const float4 boA = *(const float4*)(b_out + l15 * 8);
        const float4 boB = *(const float4*)(b_out + l15 * 8 + 4);
        float lw8[8] = {loA.x, loA.y, loA.z, loA.w, loB.x, loB.y, loB.z, loB.w};
        float lb8[8] = {lbA.x, lbA.y, lbA.z, lbA.w, lbB.x, lbB.y, lbB.z, lbB.w};
        float bo8[8] = {boA.x, boA.y, boA.z, boA.w, boB.x, boB.y, boB.z, boB.w};

        int pl = w * 4 + g;                        // [0,64)
        int iG = bi * 8 + (pl >> 3), jG = bj * 8 + (pl & 7);
        float inv = 1.0f / (EPSC + normw[iG * 256 + jG]);
        float4v zA0 = *(const float4v*)(zA + pl * 132 + l15 * 8);
        float4v zA1 = *(const float4v*)(zA + pl * 132 + l15 * 8 + 4);
        float4v zB0 = *(const float4v*)(zB + pl * 132 + l15 * 8);
        float4v zB1 = *(const float4v*)(zB + pl * 132 + l15 * 8 + 4);
        float vals[8];
        float sum = 0.f, sq = 0.f;
#pragma unroll
        for (int e2 = 0; e2 < 8; ++e2) {
            float v = ((e2 < 4) ? (zA0[e2] + zB0[e2]) : (zA1[e2 - 4] + zB1[e2 - 4])) + bo8[e2];
            v *= inv;
            v = 0.5f * v * (1.0f + erff(v * 0.70710678118654752f));
            vals[e2] = v; sum += v; sq += v * v;
        }
#pragma unroll
        for (int mm = 1; mm <= 8; mm <<= 1) {
            sum += __shfl_xor(sum, mm);
            sq  += __shfl_xor(sq, mm);
        }
        float mu = sum * (1.0f / 128.0f);
        float rstd = rsqrtf(sq * (1.0f / 128.0f) - mu * mu + 1e-5f);
        uint4 upk;
        upk.x = pk_bf16((vals[0] - mu) * rstd * lw8[0] + lb8[0],
                        (vals[1] - mu) * rstd * lw8[1] + lb8[1]);
        upk.y = pk_bf16((vals[2] - mu) * rstd * lw8[2] + lb8[2],
                        (vals[3] - mu) * rstd * lw8[3] + lb8[3]);
        upk.z = pk_bf16((vals[4] - mu) * rstd * lw8[4] + lb8[4],
                        (vals[5] - mu) * rstd * lw8[5] + lb8[5]);
        upk.w = pk_bf16((vals[6] - mu) * rstd * lw8[6] + lb8[6],
                        (vals[7] - mu) * rstd * lw8[7] + lb8[7]);
        *(uint4*)(lnL + pl * 136 + l15 * 8) = upk;
    }
    __syncthreads();

    // ------- wz matmul + bz, store; (qw 8) x (fh 2) over 16 waves -------------
    {
        int qw = w & 7, fh = w >> 3;
        float4v acc3[2]; acc3[0] = zf4; acc3[1] = zf4;
#pragma unroll
        for (int kk = 0; kk < 4; ++kk) {
            short8 bfw = *(const short8*)(wzF + ((size_t)(qw * 4 + kk) * 64 + lane) * 8);
#pragma unroll
            for (int fr2 = 0; fr2 < 2; ++fr2) {
                short8 af3 = *(const short8*)(lnL + ((fh * 2 + fr2) * 16 + l15) * 136 + kk * 32 + g * 8);
                acc3[fr2] = mfma16(af3, bfw, acc3[fr2]);
            }
        }
        float bzq = bz[qw * 16 + l15];
#pragma unroll
        for (int fr2 = 0; fr2 < 2; ++fr2) {
#pragma unroll
            for (int r = 0; r < 4; ++r) {
                int pair = (fh * 2 + fr2) * 16 + g * 4 + r;
                int row = (bi * 8 + (pair >> 3)) * 256 + bj * 8 + (pair & 7);
                out[(size_t)row * 128 + qw * 16 + l15] = acc3[fr2][r] + bzq;
            }
        }
    }
}

extern "C" void kernel_launch(void* const* d_in, const int* in_sizes, int n_in,
                              void* d_out, int out_size, void* d_ws, size_t ws_size,
                              hipStream_t stream) {
    const float* m      = (const float*)d_in[0];
    const float* mask   = (const float*)d_in[1];
    const float* ln_w   = (const float*)d_in[2];
    const float* ln_b   = (const float*)d_in[3];
    const float* w1     = (const float*)d_in[4];
    const float* b1     = (const float*)d_in[5];
    const float* w2     = (const float*)d_in[6];
    const float* b2     = (const float*)d_in[7];
    const float* w_out  = (const float*)d_in[8];
    const float* b_out  = (const float*)d_in[9];
    const float* ln_ow  = (const float*)d_in[10];
    const float* ln_ob  = (const float*)d_in[11];
    const float* wz     = (const float*)d_in[12];
    const float* bz     = (const float*)d_in[13];
    float* out = (float*)d_out;
    char*  ws  = (char*)d_ws;

    float* normw          = (float*)(ws + OFF_NORM);
    unsigned short* aTb   = (unsigned short*)(ws + OFF_AT);
    unsigned short* bTb   = (unsigned short*)(ws + OFF_BT);
    unsigned short* wobF  = (unsigned short*)(ws + OFF_WOF);
    unsigned short* wzF   = (unsigned short*)(ws + OFF_WZF);

    k_pre<<<dim3(1344), dim3(256), 0, stream>>>(m, mask, ln_w, ln_b, w1, b1, w2, b2,
                                                w_out, wz, aTb, bTb, wobF, wzF, normw);
    k2_fused<<<dim3(32, 32), dim3(1024), 0, stream>>>(aTb, bTb, wobF, wzF, b_out, normw,
                                                      ln_ow, ln_ob, bz, out);
}